// Round 5
// baseline (3658.223 us; speedup 1.0000x reference)
//
#include <hip/hip_runtime.h>
#include <hip/hip_fp16.h>

typedef unsigned int uint32;
typedef unsigned long long uint64;
typedef __attribute__((ext_vector_type(8))) _Float16 half8;
typedef __attribute__((ext_vector_type(4))) float f32x4;

#define T_STEPS 512
#define BSZ 128
#define ISZ 256
#define HSZ 512
#define K1  768            // H + I, concat order (h, x)
#define NG  8              // batch groups
#define BG  16             // batch rows per group (rows 0-7 = chain A, 8-15 = chain B)
#define GC  32             // workgroups per group (column partition)
#define NC  16             // H-columns per workgroup
#define LDK 776            // padded K stride for weights (fp16 elems)
#define LDA 264            // padded x-tile stride (fp16 elems)

// flags: per (group, rank) one 64B line; word wv = producer wave wv.
// words 0-1: chain A (waves 0-1 / rows 0-7); words 2-3: chain B (waves 2-3 / rows 8-15)
#define FLAG_U32_PER_RANK 16

// LDS layout (bytes)
#define LDS_X   0                  // x tile [16][LDA] fp16 (both chains)
#define LDS_WZ  8448
#define LDS_WR  33280
#define LDS_WH  58112
#define LDS_SCR 82944              // scR [4][16][18] f32 (rows 0-7 = A, 8-15 = B)
#define LDS_SCZ 87552              // scZ likewise
#define LDS_SCC 92160              // scC likewise
#define SMEM_BYTES 96768

// relaxed agent-scope atomics (bypass L1, L2-coherent)
#define AST(p, v) __hip_atomic_store((p), (v), __ATOMIC_RELAXED, __HIP_MEMORY_SCOPE_AGENT)
#define ALD(p)    __hip_atomic_load((p), __ATOMIC_RELAXED, __HIP_MEMORY_SCOPE_AGENT)

__device__ __forceinline__ float sigm(float x) {
  float e = __expf(-fabsf(x));
  float s = 1.f / (1.f + e);
  return x >= 0.f ? s : 1.f - s;
}
__device__ __forceinline__ float tanhx(float x) {
  float e = __expf(-2.f * fabsf(x));
  float t = (1.f - e) / (1.f + e);
  return x >= 0.f ? t : -t;
}
__device__ __forceinline__ uint32 f2x(float a, float b) {
  __half2 t = __floats2half2_rn(a, b);
  return *reinterpret_cast<uint32*>(&t);
}
#define MFMA(a, b, c) __builtin_amdgcn_mfma_f32_16x16x32_f16((a), (b), (c), 0, 0, 0)

union HF { uint64 u[2]; half8 h8; };

__global__ __launch_bounds__(256, 1)
void gru_persist(const float* __restrict__ x,
                 const float* __restrict__ Wz, const float* __restrict__ bz,
                 const float* __restrict__ Wr, const float* __restrict__ br,
                 const float* __restrict__ Wh, const float* __restrict__ bh,
                 float* __restrict__ out,
                 unsigned short* h_buf, unsigned short* rh_buf, uint32* flags)
{
  extern __shared__ char smem[];
  _Float16* X_l  = (_Float16*)(smem + LDS_X);
  _Float16* Wz_l = (_Float16*)(smem + LDS_WZ);
  _Float16* Wr_l = (_Float16*)(smem + LDS_WR);
  _Float16* Wh_l = (_Float16*)(smem + LDS_WH);
  float*    scR  = (float*)(smem + LDS_SCR);
  float*    scZ  = (float*)(smem + LDS_SCZ);
  float*    scC  = (float*)(smem + LDS_SCC);

  const int tid  = threadIdx.x;
  const int g    = blockIdx.x & 7;                // group -> same XCD (round-robin dispatch)
  const int rank = blockIdx.x >> 3;
  uint32* gf = flags + (size_t)g * GC * FLAG_U32_PER_RANK;
  unsigned short* hbG  = h_buf  + (size_t)g * BG * HSZ;
  unsigned short* rhbG = rh_buf + (size_t)g * BG * HSZ;

  // ---- one-time: weight slices -> LDS fp16 ----
  {
    const int r  = tid & 15;
    const int ch = tid >> 4;
    for (int mi = 0; mi < 3; ++mi) {
      const float* Ws = (mi == 0) ? Wz : (mi == 1 ? Wr : Wh);
      _Float16*    Ld = (mi == 0) ? Wz_l : (mi == 1 ? Wr_l : Wh_l);
      const float4* s = (const float4*)(Ws + (size_t)(rank * NC + r) * K1 + ch * 48);
      uint4* d = (uint4*)(Ld + r * LDK + ch * 48);
      #pragma unroll
      for (int j = 0; j < 6; ++j) {
        float4 v0 = s[2 * j], v1 = s[2 * j + 1];
        d[j] = make_uint4(f2x(v0.x, v0.y), f2x(v0.z, v0.w),
                          f2x(v1.x, v1.y), f2x(v1.z, v1.w));
      }
    }
  }

  // elementwise map: (batch bl, col cl). bl<8 -> chain A (waves 0-1), bl>=8 -> chain B (waves 2-3)
  const int cl = tid & 15, bl = tid >> 4;
  // staging map: consecutive lanes -> consecutive rows
  const int bl2 = tid & 15, cl2 = tid >> 4;
  const int cg = rank * NC + cl;
  const int bg = g * BG + bl;
  const int bg2 = g * BG + bl2;
  const float bz_r = bz[cg], br_r = br[cg], bh_r = bh[cg];

  float h_reg = 0.f;

  const int wv = tid >> 6, lane = tid & 63;
  const int mrow = lane & 15, q = lane >> 4;
  const int scO = bl * 18 + cl;
  const bool loA   = (wv < 2);          // thread's elementwise chain
  const bool liveA = (mrow < 8);        // frag lane belongs to chain A rows
  const bool qlo   = (q < 2);           // D rows 0-7 (chain A sc region)

  // fragment bases: lane (wv,q,mrow) reads row mrow, cols wv*128+q*8 + {0,32,64,96}
  const uint64* hfb = (const uint64*)(hbG  + (size_t)mrow * HSZ + wv * 128 + q * 8);
  const uint64* rfb = (const uint64*)(rhbG + (size_t)mrow * HSZ + wv * 128 + q * 8);
  // producer flag word for this wave
  uint32* myflag = gf + (size_t)rank * FLAG_U32_PER_RANK + wv;
  // centralized poll ptrs (tid<64): rank tid>>1, word chain*2 + (tid&1)
  const uint32* pollA = gf + (size_t)(tid >> 1) * FLAG_U32_PER_RANK + (tid & 1);
  const uint32* pollB = pollA + 2;

  // stage x[0]
  float4 px0, px1, px2, px3;
  {
    const float4* xs = (const float4*)(x + (size_t)bg2 * ISZ + cl2 * 16);
    px0 = xs[0]; px1 = xs[1]; px2 = xs[2]; px3 = xs[3];
    uint4* xd = (uint4*)(X_l + bl2 * LDA + cl2 * 16);
    xd[0] = make_uint4(f2x(px0.x, px0.y), f2x(px0.z, px0.w),
                       f2x(px1.x, px1.y), f2x(px1.z, px1.w));
    xd[1] = make_uint4(f2x(px2.x, px2.y), f2x(px2.z, px2.w),
                       f2x(px3.x, px3.y), f2x(px3.z, px3.w));
  }
  __syncthreads();

  for (int t = 0; t < T_STEPS; ++t) {
    // ---- P1: x-part MFMAs for r,z,cand (K=64 slice per wave; rows 0-15 = both chains) ----
    f32x4 accR = {0.f, 0.f, 0.f, 0.f};
    f32x4 aR1  = {0.f, 0.f, 0.f, 0.f};
    f32x4 accZ = {0.f, 0.f, 0.f, 0.f};
    f32x4 accC = {0.f, 0.f, 0.f, 0.f};
    f32x4 aC1  = {0.f, 0.f, 0.f, 0.f};
    {
      const int kbx = wv * 64;
      const half8* Ap  = (const half8*)(X_l  + mrow * LDA + kbx + q * 8);
      const half8* BpR = (const half8*)(Wr_l + mrow * LDK + HSZ + kbx + q * 8);
      const half8* BpZ = (const half8*)(Wz_l + mrow * LDK + HSZ + kbx + q * 8);
      const half8* BpC = (const half8*)(Wh_l + mrow * LDK + HSZ + kbx + q * 8);
      half8 a0 = Ap[0], a1 = Ap[4];
      accR = MFMA(a0, BpR[0], accR);
      accZ = MFMA(a0, BpZ[0], accZ);
      accC = MFMA(a0, BpC[0], accC);
      accR = MFMA(a1, BpR[4], accR);
      accZ = MFMA(a1, BpZ[4], accZ);
      accC = MFMA(a1, BpC[4], accC);
    }
    // preload r h-part weight fragments (shared by both chains)
    half8 br0, br1, br2, br3;
    {
      const half8* Bp = (const half8*)(Wr_l + mrow * LDK + wv * 128 + q * 8);
      br0 = Bp[0]; br1 = Bp[4]; br2 = Bp[8]; br3 = Bp[12];
    }

    // ---- RH_A: h frags (chain A rows, others 0) -> r MFMA; scR rows 0-7 ----
    // gated by hA >= 2t poll done before B1e of previous iteration
    HF fh0, fh1, fh2, fh3;
    fh0.u[0] = fh0.u[1] = fh1.u[0] = fh1.u[1] = 0;
    fh2.u[0] = fh2.u[1] = fh3.u[0] = fh3.u[1] = 0;
    if (liveA) {
      fh0.u[0] = ALD(hfb +  0); fh0.u[1] = ALD(hfb +  1);
      fh1.u[0] = ALD(hfb +  8); fh1.u[1] = ALD(hfb +  9);
      fh2.u[0] = ALD(hfb + 16); fh2.u[1] = ALD(hfb + 17);
      fh3.u[0] = ALD(hfb + 24); fh3.u[1] = ALD(hfb + 25);
    }
    accR = MFMA(fh0.h8, br0, accR);
    aR1  = MFMA(fh1.h8, br1, aR1);
    accR = MFMA(fh2.h8, br2, accR);
    aR1  = MFMA(fh3.h8, br3, aR1);
    if (qlo) {
      float* scw = scR + wv * 288;
      #pragma unroll
      for (int i = 0; i < 4; ++i) scw[(q * 4 + i) * 18 + mrow] = accR[i] + aR1[i];
    }
    if (tid < 64) {                      // poll hB >= 2t (for RH_B)
      const uint32 need = (uint32)(2 * t);
      while (ALD(pollB) < need) {}
    }
    __syncthreads();   // B1b

    // ---- RH_A tail: r elementwise A; publish rhA; per-wave drain; flag; prefetch ----
    if (loA) {
      float rp = scR[scO] + scR[288 + scO] + scR[576 + scO] + scR[864 + scO] + br_r;
      float rhv = sigm(rp) * h_reg;
      __half hh = __float2half(rhv);
      uint32 lo = (uint32)__half_as_ushort(hh);
      uint32 hi = (uint32)__shfl_down((int)lo, 1);
      if (!(tid & 1))
        AST((uint32*)(rhbG + bl * HSZ + rank * NC + cl), lo | (hi << 16));
      asm volatile("s_waitcnt vmcnt(0)" ::: "memory");
      if (lane == 0) AST(myflag, (uint32)(2 * t + 1));
      if (t + 1 < T_STEPS) {             // prefetch own x quarter (after drain: no extension)
        const float4* xs = (const float4*)(x + ((size_t)(t + 1) * BSZ + bg2) * ISZ + cl2 * 16);
        px0 = xs[0]; px1 = xs[1]; px2 = xs[2]; px3 = xs[3];
      }
    }
    // z h-part chain A (rh round-trip shadow)
    {
      const half8* Bp = (const half8*)(Wz_l + mrow * LDK + wv * 128 + q * 8);
      accZ = MFMA(fh0.h8, Bp[0], accZ);
      accZ = MFMA(fh1.h8, Bp[4], accZ);
      accZ = MFMA(fh2.h8, Bp[8], accZ);
      accZ = MFMA(fh3.h8, Bp[12], accZ);
      if (qlo) {
        float* scw = scZ + wv * 288;
        #pragma unroll
        for (int i = 0; i < 4; ++i) scw[(q * 4 + i) * 18 + mrow] = accZ[i];
      }
    }

    // ---- RH_B: h frags (chain B rows, others 0) -> r MFMA; scR rows 8-15 ----
    fh0.u[0] = fh0.u[1] = fh1.u[0] = fh1.u[1] = 0;
    fh2.u[0] = fh2.u[1] = fh3.u[0] = fh3.u[1] = 0;
    if (!liveA) {
      fh0.u[0] = ALD(hfb +  0); fh0.u[1] = ALD(hfb +  1);
      fh1.u[0] = ALD(hfb +  8); fh1.u[1] = ALD(hfb +  9);
      fh2.u[0] = ALD(hfb + 16); fh2.u[1] = ALD(hfb + 17);
      fh3.u[0] = ALD(hfb + 24); fh3.u[1] = ALD(hfb + 25);
    }
    accR = MFMA(fh0.h8, br0, accR);
    aR1  = MFMA(fh1.h8, br1, aR1);
    accR = MFMA(fh2.h8, br2, accR);
    aR1  = MFMA(fh3.h8, br3, aR1);
    if (!qlo) {
      float* scw = scR + wv * 288;
      #pragma unroll
      for (int i = 0; i < 4; ++i) scw[(q * 4 + i) * 18 + mrow] = accR[i] + aR1[i];
    }
    if (tid < 64) {                      // poll rhA >= 2t+1 (for CAND_A)
      const uint32 need = (uint32)(2 * t + 1);
      while (ALD(pollA) < need) {}
    }
    __syncthreads();   // B1c

    // ---- RH_B tail: r elementwise B; publish rhB; drain; flag; prefetch ----
    if (!loA) {
      float rp = scR[scO] + scR[288 + scO] + scR[576 + scO] + scR[864 + scO] + br_r;
      float rhv = sigm(rp) * h_reg;
      __half hh = __float2half(rhv);
      uint32 lo = (uint32)__half_as_ushort(hh);
      uint32 hi = (uint32)__shfl_down((int)lo, 1);
      if (!(tid & 1))
        AST((uint32*)(rhbG + bl * HSZ + rank * NC + cl), lo | (hi << 16));
      asm volatile("s_waitcnt vmcnt(0)" ::: "memory");
      if (lane == 0) AST(myflag, (uint32)(2 * t + 1));
      if (t + 1 < T_STEPS) {
        const float4* xs = (const float4*)(x + ((size_t)(t + 1) * BSZ + bg2) * ISZ + cl2 * 16);
        px0 = xs[0]; px1 = xs[1]; px2 = xs[2]; px3 = xs[3];
      }
    }
    // z h-part chain B (shadow)
    {
      const half8* Bp = (const half8*)(Wz_l + mrow * LDK + wv * 128 + q * 8);
      accZ = MFMA(fh0.h8, Bp[0], accZ);
      accZ = MFMA(fh1.h8, Bp[4], accZ);
      accZ = MFMA(fh2.h8, Bp[8], accZ);
      accZ = MFMA(fh3.h8, Bp[12], accZ);
      if (!qlo) {
        float* scw = scZ + wv * 288;
        #pragma unroll
        for (int i = 0; i < 4; ++i) scw[(q * 4 + i) * 18 + mrow] = accZ[i];
      }
    }
    // preload cand h-part weight fragments (shared by both chains)
    half8 bc0, bc1, bc2, bc3;
    {
      const half8* Bp = (const half8*)(Wh_l + mrow * LDK + wv * 128 + q * 8);
      bc0 = Bp[0]; bc1 = Bp[4]; bc2 = Bp[8]; bc3 = Bp[12];
    }

    // ---- CAND_A: rh frags (chain A) -> cand MFMA; scC rows 0-7 ----
    {
      HF fc0, fc1, fc2, fc3;
      fc0.u[0] = fc0.u[1] = fc1.u[0] = fc1.u[1] = 0;
      fc2.u[0] = fc2.u[1] = fc3.u[0] = fc3.u[1] = 0;
      if (liveA) {
        fc0.u[0] = ALD(rfb +  0); fc0.u[1] = ALD(rfb +  1);
        fc1.u[0] = ALD(rfb +  8); fc1.u[1] = ALD(rfb +  9);
        fc2.u[0] = ALD(rfb + 16); fc2.u[1] = ALD(rfb + 17);
        fc3.u[0] = ALD(rfb + 24); fc3.u[1] = ALD(rfb + 25);
      }
      accC = MFMA(fc0.h8, bc0, accC);
      aC1  = MFMA(fc1.h8, bc1, aC1);
      accC = MFMA(fc2.h8, bc2, accC);
      aC1  = MFMA(fc3.h8, bc3, aC1);
      if (qlo) {
        float* scw = scC + wv * 288;
        #pragma unroll
        for (int i = 0; i < 4; ++i) scw[(q * 4 + i) * 18 + mrow] = accC[i] + aC1[i];
      }
    }
    if (tid < 64) {                      // poll rhB >= 2t+1 (for CAND_B)
      const uint32 need = (uint32)(2 * t + 1);
      while (ALD(pollB) < need) {}
    }
    __syncthreads();   // B1d

    // ---- CAND_A tail: z finish + cand + h update A; publish hA; drain; flag; out ----
    if (loA) {
      float zp = scZ[scO] + scZ[288 + scO] + scZ[576 + scO] + scZ[864 + scO] + bz_r;
      float zg = sigm(zp);
      float cp = scC[scO] + scC[288 + scO] + scC[576 + scO] + scC[864 + scO] + bh_r;
      float cand = tanhx(cp);
      float hn = (1.f - zg) * h_reg + zg * cand;
      h_reg = hn;
      __half hh = __float2half(hn);
      uint32 lo = (uint32)__half_as_ushort(hh);
      uint32 hi = (uint32)__shfl_down((int)lo, 1);
      if (!(tid & 1))
        AST((uint32*)(hbG + bl * HSZ + rank * NC + cl), lo | (hi << 16));
      asm volatile("s_waitcnt vmcnt(0)" ::: "memory");
      if (lane == 0) AST(myflag, (uint32)(2 * t + 2));
      out[((size_t)t * BSZ + bg) * HSZ + cg] = hn;
      if (t == T_STEPS - 1)
        out[((size_t)T_STEPS * BSZ + bg) * HSZ + cg] = hn;   // h_last
    }
    // stage x_{t+1} (all threads; fenced from P1(t+1) reads by B1e)
    if (t + 1 < T_STEPS) {
      uint4* xd = (uint4*)(X_l + bl2 * LDA + cl2 * 16);
      xd[0] = make_uint4(f2x(px0.x, px0.y), f2x(px0.z, px0.w),
                         f2x(px1.x, px1.y), f2x(px1.z, px1.w));
      xd[1] = make_uint4(f2x(px2.x, px2.y), f2x(px2.z, px2.w),
                         f2x(px3.x, px3.y), f2x(px3.z, px3.w));
    }

    // ---- CAND_B: rh frags (chain B) -> cand MFMA; scC rows 8-15 ----
    {
      HF fc0, fc1, fc2, fc3;
      fc0.u[0] = fc0.u[1] = fc1.u[0] = fc1.u[1] = 0;
      fc2.u[0] = fc2.u[1] = fc3.u[0] = fc3.u[1] = 0;
      if (!liveA) {
        fc0.u[0] = ALD(rfb +  0); fc0.u[1] = ALD(rfb +  1);
        fc1.u[0] = ALD(rfb +  8); fc1.u[1] = ALD(rfb +  9);
        fc2.u[0] = ALD(rfb + 16); fc2.u[1] = ALD(rfb + 17);
        fc3.u[0] = ALD(rfb + 24); fc3.u[1] = ALD(rfb + 25);
      }
      accC = MFMA(fc0.h8, bc0, accC);
      aC1  = MFMA(fc1.h8, bc1, aC1);
      accC = MFMA(fc2.h8, bc2, accC);
      aC1  = MFMA(fc3.h8, bc3, aC1);
      if (!qlo) {
        float* scw = scC + wv * 288;
        #pragma unroll
        for (int i = 0; i < 4; ++i) scw[(q * 4 + i) * 18 + mrow] = accC[i] + aC1[i];
      }
    }
    if (tid < 64) {                      // poll hA >= 2t+2 (for RH_A of t+1)
      const uint32 need = (uint32)(2 * t + 2);
      while (ALD(pollA) < need) {}
    }
    __syncthreads();   // B1e

    // ---- CAND_B tail: z finish + cand + h update B; publish hB; drain; flag; out ----
    if (!loA) {
      float zp = scZ[scO] + scZ[288 + scO] + scZ[576 + scO] + scZ[864 + scO] + bz_r;
      float zg = sigm(zp);
      float cp = scC[scO] + scC[288 + scO] + scC[576 + scO] + scC[864 + scO] + bh_r;
      float cand = tanhx(cp);
      float hn = (1.f - zg) * h_reg + zg * cand;
      h_reg = hn;
      __half hh = __float2half(hn);
      uint32 lo = (uint32)__half_as_ushort(hh);
      uint32 hi = (uint32)__shfl_down((int)lo, 1);
      if (!(tid & 1))
        AST((uint32*)(hbG + bl * HSZ + rank * NC + cl), lo | (hi << 16));
      asm volatile("s_waitcnt vmcnt(0)" ::: "memory");
      if (lane == 0) AST(myflag, (uint32)(2 * t + 2));
      out[((size_t)t * BSZ + bg) * HSZ + cg] = hn;
      if (t == T_STEPS - 1)
        out[((size_t)T_STEPS * BSZ + bg) * HSZ + cg] = hn;   // h_last
    }
  }
}

extern "C" void kernel_launch(void* const* d_in, const int* in_sizes, int n_in,
                              void* d_out, int out_size, void* d_ws, size_t ws_size,
                              hipStream_t stream) {
  const float* x  = (const float*)d_in[0];
  const float* Wz = (const float*)d_in[1];
  const float* bz = (const float*)d_in[2];
  const float* Wr = (const float*)d_in[3];
  const float* br = (const float*)d_in[4];
  const float* Wh = (const float*)d_in[5];
  const float* bh = (const float*)d_in[6];
  float* out = (float*)d_out;

  // ws layout: [flags 8 groups * 32 ranks * 64B = 16KB][h_buf 128KB][rh_buf 128KB]
  uint32* flags = (uint32*)d_ws;
  unsigned short* h_buf  = (unsigned short*)((char*)d_ws + NG * GC * FLAG_U32_PER_RANK * 4);
  unsigned short* rh_buf = h_buf + NG * BG * HSZ;

  // zero flags + h0 (rh_buf is written before first read; no clear needed)
  hipMemsetAsync(d_ws, 0, NG * GC * FLAG_U32_PER_RANK * 4 + (size_t)NG * BG * HSZ * 2, stream);

  hipFuncSetAttribute(reinterpret_cast<const void*>(gru_persist),
                      hipFuncAttributeMaxDynamicSharedMemorySize, SMEM_BYTES);

  hipLaunchKernelGGL(gru_persist, dim3(NG * GC), dim3(256), SMEM_BYTES, stream,
                     x, Wz, bz, Wr, br, Wh, bh, out, h_buf, rh_buf, flags);
}

// Round 6
// 2334.032 us; speedup vs baseline: 1.5673x; 1.5673x over previous
//
#include <hip/hip_runtime.h>
#include <hip/hip_fp16.h>

typedef unsigned int uint32;
typedef unsigned long long uint64;
typedef __attribute__((ext_vector_type(8))) _Float16 half8;
typedef __attribute__((ext_vector_type(4))) float f32x4;

#define T_STEPS 512
#define BSZ 128
#define ISZ 256
#define HSZ 512
#define K1  768            // H + I, concat order (h, x)
#define NG  8              // batch groups
#define BG  16             // batch rows per group
#define GC  32             // workgroups per group (column partition)
#define NC  16             // H-columns per workgroup
#define LDK 776            // padded K stride for weights (fp16 elems)
#define LDA 264            // padded x-tile stride (fp16 elems)
#define FSTRIDE 32         // u32 per rank flag -> own 128B L2 line

// Exchange buffers are TILED BY PRODUCER RANK:
//   buf[g][rank][sel(2)][row(16)][q1(2)] of u64   (rank tile = 512B contiguous)
// element (row, col) fp16: u64idx = col>>2, sel = u64idx&1, q1 = u64idx>>1
// byte offset within tile = sel*256 + row*16 + q1*8
// -> consumer fragment-load instructions cover contiguous 256B segments (2-4 L2
//    requests/inst instead of 16); producer publish = 2 coalesced 64B bursts/wave.

// LDS layout (bytes)
#define LDS_X   0                  // x tile [16][LDA] fp16
#define LDS_WZ  8448
#define LDS_WR  33280
#define LDS_WH  58112
#define LDS_SC  82944              // scratch [4][16][18] fp32 (stride 18 -> 2-way max)
#define SMEM_BYTES 87552

// relaxed agent-scope atomics (bypass L1, L2-coherent)
#define AST(p, v) __hip_atomic_store((p), (v), __ATOMIC_RELAXED, __HIP_MEMORY_SCOPE_AGENT)
#define ALD(p)    __hip_atomic_load((p), __ATOMIC_RELAXED, __HIP_MEMORY_SCOPE_AGENT)

__device__ __forceinline__ float sigm(float x) {
  float e = __expf(-fabsf(x));
  float s = 1.f / (1.f + e);
  return x >= 0.f ? s : 1.f - s;
}
__device__ __forceinline__ float tanhx(float x) {
  float e = __expf(-2.f * fabsf(x));
  float t = (1.f - e) / (1.f + e);
  return x >= 0.f ? t : -t;
}
__device__ __forceinline__ uint32 f2x(float a, float b) {
  __half2 t = __floats2half2_rn(a, b);
  return *reinterpret_cast<uint32*>(&t);
}
#define MFMA(a, b, c) __builtin_amdgcn_mfma_f32_16x16x32_f16((a), (b), (c), 0, 0, 0)

union HF { uint64 u[2]; half8 h8; };

__global__ __launch_bounds__(256, 1)
void gru_persist(const float* __restrict__ x,
                 const float* __restrict__ Wz, const float* __restrict__ bz,
                 const float* __restrict__ Wr, const float* __restrict__ br,
                 const float* __restrict__ Wh, const float* __restrict__ bh,
                 float* __restrict__ out,
                 unsigned short* h_buf, unsigned short* rh_buf, uint32* flags)
{
  extern __shared__ char smem[];
  _Float16* X_l  = (_Float16*)(smem + LDS_X);
  _Float16* Wz_l = (_Float16*)(smem + LDS_WZ);
  _Float16* Wr_l = (_Float16*)(smem + LDS_WR);
  _Float16* Wh_l = (_Float16*)(smem + LDS_WH);
  float*    sc   = (float*)(smem + LDS_SC);

  const int tid  = threadIdx.x;
  const int g    = blockIdx.x & 7;                // group -> same XCD (round-robin dispatch)
  const int rank = blockIdx.x >> 3;
  uint32* gf = flags + (size_t)g * GC * FSTRIDE;  // 128B-padded per-rank flags
  char* hbG  = (char*)(h_buf  + (size_t)g * GC * 256);   // 16KB tiled region per group
  char* rhbG = (char*)(rh_buf + (size_t)g * GC * 256);

  // ---- one-time: weight slices -> LDS fp16 ----
  {
    const int r  = tid & 15;
    const int ch = tid >> 4;
    for (int mi = 0; mi < 3; ++mi) {
      const float* Ws = (mi == 0) ? Wz : (mi == 1 ? Wr : Wh);
      _Float16*    Ld = (mi == 0) ? Wz_l : (mi == 1 ? Wr_l : Wh_l);
      const float4* s = (const float4*)(Ws + (size_t)(rank * NC + r) * K1 + ch * 48);
      uint4* d = (uint4*)(Ld + r * LDK + ch * 48);
      #pragma unroll
      for (int j = 0; j < 6; ++j) {
        float4 v0 = s[2 * j], v1 = s[2 * j + 1];
        d[j] = make_uint4(f2x(v0.x, v0.y), f2x(v0.z, v0.w),
                          f2x(v1.x, v1.y), f2x(v1.z, v1.w));
      }
    }
  }

  // elementwise map: (batch bl, col cl)
  const int cl = tid & 15, bl = tid >> 4;
  // staging map: consecutive lanes -> consecutive rows
  const int bl2 = tid & 15, cl2 = tid >> 4;
  const int cg = rank * NC + cl;
  const int bg = g * BG + bl;
  const int bg2 = g * BG + bl2;
  const float bz_r = bz[cg], br_r = br[cg], bh_r = bh[cg];

  float h_reg = 0.f, zg = 0.f;

  const int wv = tid >> 6, lane = tid & 63;
  const int mrow = lane & 15, q = lane >> 4;
  const int scO = bl * 18 + cl;

  // publish address (tiled): element (bl, cl..cl+1) as u32
  const int pub_idx = cl >> 2;                    // u64 within row
  const int pub_off = (pub_idx & 1) * 256 + bl * 16 + (pub_idx >> 1) * 8 + ((cl >> 1) & 1) * 4;
  uint32* rh_pub = (uint32*)(rhbG + rank * 512 + pub_off);
  uint32* h_pub  = (uint32*)(hbG  + rank * 512 + pub_off);

  // consumer fragment base (u64 units): rank (8wv + (q>>1)), row mrow, half (q&1)
  // frag kk: u[sel] at base + kk*128 + sel*32
  const size_t fragO = (size_t)(8 * wv + (q >> 1)) * 64 + mrow * 2 + (q & 1);
  const uint64* hfb = (const uint64*)hbG  + fragO;
  const uint64* rfb = (const uint64*)rhbG + fragO;

  // stage x[0], prefetch x[1]
  float4 px0, px1, px2, px3;
  {
    const float4* xs = (const float4*)(x + (size_t)bg2 * ISZ + cl2 * 16);
    px0 = xs[0]; px1 = xs[1]; px2 = xs[2]; px3 = xs[3];
    uint4* xd = (uint4*)(X_l + bl2 * LDA + cl2 * 16);
    xd[0] = make_uint4(f2x(px0.x, px0.y), f2x(px0.z, px0.w),
                       f2x(px1.x, px1.y), f2x(px1.z, px1.w));
    xd[1] = make_uint4(f2x(px2.x, px2.y), f2x(px2.z, px2.w),
                       f2x(px3.x, px3.y), f2x(px3.z, px3.w));
    const float4* xs1 = (const float4*)(x + ((size_t)1 * BSZ + bg2) * ISZ + cl2 * 16);
    px0 = xs1[0]; px1 = xs1[1]; px2 = xs1[2]; px3 = xs1[3];
  }
  __syncthreads();

  for (int t = 0; t < T_STEPS; ++t) {
    // ---- S1: x-part MFMAs for r,z,cand (K=64 slice per wave), then poll h ----
    f32x4 acc1 = {0.f, 0.f, 0.f, 0.f};   // unused placeholder removed
    f32x4 accR = {0.f, 0.f, 0.f, 0.f};
    f32x4 accZ = {0.f, 0.f, 0.f, 0.f};
    f32x4 accC = {0.f, 0.f, 0.f, 0.f};
    {
      const int kbx = wv * 64;
      const half8* Ap  = (const half8*)(X_l  + mrow * LDA + kbx + q * 8);
      const half8* BpR = (const half8*)(Wr_l + mrow * LDK + HSZ + kbx + q * 8);
      const half8* BpZ = (const half8*)(Wz_l + mrow * LDK + HSZ + kbx + q * 8);
      const half8* BpC = (const half8*)(Wh_l + mrow * LDK + HSZ + kbx + q * 8);
      half8 a0 = Ap[0], a1 = Ap[4];
      accR = MFMA(a0, BpR[0], accR);
      accZ = MFMA(a0, BpZ[0], accZ);
      accC = MFMA(a0, BpC[0], accC);
      accR = MFMA(a1, BpR[4], accR);
      accZ = MFMA(a1, BpZ[4], accZ);
      accC = MFMA(a1, BpC[4], accC);
    }
    (void)acc1;

    // pre-load r weight fragments (poll shadow)
    half8 br0, br1, br2, br3;
    {
      const half8* BpR = (const half8*)(Wr_l + mrow * LDK + wv * 128 + q * 8);
      br0 = BpR[0]; br1 = BpR[4]; br2 = BpR[8]; br3 = BpR[12];
    }

    // ---- poll h flags (2t) ----
    if (tid < GC) {
      const uint32 need = (uint32)(2 * t);
      while (ALD(gf + tid * FSTRIDE) < need) {}
    }
    __syncthreads();   // B1

    // ---- P2: direct tiled L2 fragment loads -> r h-MFMA ----
    HF fh0, fh1, fh2, fh3;
    {
      fh0.u[0] = ALD(hfb +   0); fh0.u[1] = ALD(hfb +  32);
      fh1.u[0] = ALD(hfb + 128); fh1.u[1] = ALD(hfb + 160);
      fh2.u[0] = ALD(hfb + 256); fh2.u[1] = ALD(hfb + 288);
      fh3.u[0] = ALD(hfb + 384); fh3.u[1] = ALD(hfb + 416);
      f32x4 aR1 = {0.f, 0.f, 0.f, 0.f};
      accR = MFMA(fh0.h8, br0, accR);
      aR1  = MFMA(fh1.h8, br1, aR1);
      accR = MFMA(fh2.h8, br2, accR);
      aR1  = MFMA(fh3.h8, br3, aR1);
      float* scw = sc + wv * 288;
      #pragma unroll
      for (int i = 0; i < 4; ++i) scw[(q * 4 + i) * 18 + mrow] = accR[i] + aR1[i];
    }
    __syncthreads();   // B2

    // ---- P3: r elementwise; publish rh (flag 2t+1) ----
    {
      float rp = sc[scO] + sc[288 + scO] + sc[576 + scO] + sc[864 + scO] + br_r;
      float rhv = sigm(rp) * h_reg;
      __half hh = __float2half(rhv);
      uint32 lo = (uint32)__half_as_ushort(hh);
      uint32 hi = (uint32)__shfl_down((int)lo, 1);
      if (!(tid & 1)) AST(rh_pub, lo | (hi << 16));
    }
    asm volatile("s_waitcnt vmcnt(0)" ::: "memory");
    __syncthreads();   // B3
    if (tid == 0) AST(gf + rank * FSTRIDE, (uint32)(2 * t + 1));

    // ---- P4 (rh round-trip shadow): z h-part (reuse fh regs); x staging; x prefetch ----
    {
      const half8* BpZ = (const half8*)(Wz_l + mrow * LDK + wv * 128 + q * 8);
      accZ = MFMA(fh0.h8, BpZ[0], accZ);
      accZ = MFMA(fh1.h8, BpZ[4], accZ);
      accZ = MFMA(fh2.h8, BpZ[8], accZ);
      accZ = MFMA(fh3.h8, BpZ[12], accZ);
      float* scw = sc + wv * 288;
      #pragma unroll
      for (int i = 0; i < 4; ++i) scw[(q * 4 + i) * 18 + mrow] = accZ[i];
    }
    if (t + 1 < T_STEPS) {     // stage x_{t+1} (loaded last iteration)
      uint4* xd = (uint4*)(X_l + bl2 * LDA + cl2 * 16);
      xd[0] = make_uint4(f2x(px0.x, px0.y), f2x(px0.z, px0.w),
                         f2x(px1.x, px1.y), f2x(px1.z, px1.w));
      xd[1] = make_uint4(f2x(px2.x, px2.y), f2x(px2.z, px2.w),
                         f2x(px3.x, px3.y), f2x(px3.z, px3.w));
    }
    if (t + 2 < T_STEPS) {     // prefetch x_{t+2}
      const float4* xs = (const float4*)(x + ((size_t)(t + 2) * BSZ + bg2) * ISZ + cl2 * 16);
      px0 = xs[0]; px1 = xs[1]; px2 = xs[2]; px3 = xs[3];
    }
    __syncthreads();   // B4

    // ---- S5: finish z (VALU under poll); pre-load cand weight frags; poll rh ----
    {
      float zp = sc[scO] + sc[288 + scO] + sc[576 + scO] + sc[864 + scO] + bz_r;
      zg = sigm(zp);
    }
    half8 bc0, bc1, bc2, bc3;
    {
      const half8* BpC = (const half8*)(Wh_l + mrow * LDK + wv * 128 + q * 8);
      bc0 = BpC[0]; bc1 = BpC[4]; bc2 = BpC[8]; bc3 = BpC[12];
    }
    if (tid < GC) {
      const uint32 need = (uint32)(2 * t + 1);
      while (ALD(gf + tid * FSTRIDE) < need) {}
    }
    __syncthreads();   // B5

    // ---- P6: direct tiled rh fragment loads -> cand MFMA ----
    {
      HF fc0, fc1, fc2, fc3;
      fc0.u[0] = ALD(rfb +   0); fc0.u[1] = ALD(rfb +  32);
      fc1.u[0] = ALD(rfb + 128); fc1.u[1] = ALD(rfb + 160);
      fc2.u[0] = ALD(rfb + 256); fc2.u[1] = ALD(rfb + 288);
      fc3.u[0] = ALD(rfb + 384); fc3.u[1] = ALD(rfb + 416);
      f32x4 aC1 = {0.f, 0.f, 0.f, 0.f};
      accC = MFMA(fc0.h8, bc0, accC);
      aC1  = MFMA(fc1.h8, bc1, aC1);
      accC = MFMA(fc2.h8, bc2, accC);
      aC1  = MFMA(fc3.h8, bc3, aC1);
      float* scw = sc + wv * 288;
      #pragma unroll
      for (int i = 0; i < 4; ++i) scw[(q * 4 + i) * 18 + mrow] = accC[i] + aC1[i];
    }
    __syncthreads();   // B6

    // ---- P7: cand, h update, publish h (flag 2t+2); out store after flag ----
    float hn;
    {
      float cp = sc[scO] + sc[288 + scO] + sc[576 + scO] + sc[864 + scO] + bh_r;
      float cand = tanhx(cp);
      hn = (1.f - zg) * h_reg + zg * cand;
      h_reg = hn;
      __half hh = __float2half(hn);
      uint32 lo = (uint32)__half_as_ushort(hh);
      uint32 hi = (uint32)__shfl_down((int)lo, 1);
      if (!(tid & 1)) AST(h_pub, lo | (hi << 16));
    }
    asm volatile("s_waitcnt vmcnt(0)" ::: "memory");
    __syncthreads();   // B7
    if (tid == 0) AST(gf + rank * FSTRIDE, (uint32)(2 * t + 2));

    // out (HBM) store drains in the background of the next h round-trip
    out[((size_t)t * BSZ + bg) * HSZ + cg] = hn;
    if (t == T_STEPS - 1)
      out[((size_t)T_STEPS * BSZ + bg) * HSZ + cg] = hn;   // h_last
  }
}

extern "C" void kernel_launch(void* const* d_in, const int* in_sizes, int n_in,
                              void* d_out, int out_size, void* d_ws, size_t ws_size,
                              hipStream_t stream) {
  const float* x  = (const float*)d_in[0];
  const float* Wz = (const float*)d_in[1];
  const float* bz = (const float*)d_in[2];
  const float* Wr = (const float*)d_in[3];
  const float* br = (const float*)d_in[4];
  const float* Wh = (const float*)d_in[5];
  const float* bh = (const float*)d_in[6];
  float* out = (float*)d_out;

  // ws layout: [flags 8*32*128B = 32KB][h_buf 128KB][rh_buf 128KB]
  uint32* flags = (uint32*)d_ws;
  unsigned short* h_buf  = (unsigned short*)((char*)d_ws + NG * GC * FSTRIDE * 4);
  unsigned short* rh_buf = h_buf + NG * GC * 256;

  // zero flags + h0 (rh_buf is written before first read; no clear needed)
  hipMemsetAsync(d_ws, 0, NG * GC * FSTRIDE * 4 + (size_t)NG * GC * 256 * 2, stream);

  hipFuncSetAttribute(reinterpret_cast<const void*>(gru_persist),
                      hipFuncAttributeMaxDynamicSharedMemorySize, SMEM_BYTES);

  hipLaunchKernelGGL(gru_persist, dim3(NG * GC), dim3(256), SMEM_BYTES, stream,
                     x, Wz, bz, Wr, br, Wh, bh, out, h_buf, rh_buf, flags);
}